// Round 16
// baseline (357.264 us; speedup 1.0000x reference)
//
#include <hip/hip_runtime.h>
#include <string.h>

// TopographicIntentMap R16: R15 (354us, best) + dual f64 accumulators.
// R15 accounting: per-SIMD VALU ~527K cyc (f64 cvt/fma issue at ~8cy) and DS
// ~436K cyc/CU do NOT overlap -- within a wave every gather chains
// ds_read -> cvt -> fma on ONE rec, and only 4 barrier-synced waves/SIMD
// exist to hide the latency. Fix: alternate entries into rec0/rec1 (R12's
// validated mechanism, without R12's b64-gather regression): halves the
// dependent chain, one chain's FMAs hide the other's ds_read latency.
// Diff vs R15 is the GFMA4 macro + rec declaration ONLY: same b32 gathers,
// same snake-balanced stream, same one tick body, same f32 acc dbuf.
// Numerics: rec0+rec1 = exact-f64-class reassociation, empirically absmax 0
// across 7 different associations (R4-R15); LIF verbatim; pads +0.0.

#define NN 144
#define NE 115
#define NB 64            // batches per block (= lanes)
#define SLOTS 9          // rows per wave: 16*9 = 144
#define THREADS 1024

#define STREAM_BASE 4096 // stream region in ws (bytes); meta at ws[0..2KB)
#define META_STRIDE 32   // ints per wave: [0]=base entry idx, [1+r]=row, [10+r]=kp

__device__ __forceinline__ float u2f(unsigned u) {
    float f; memcpy(&f, &u, 4); return f;
}

__global__ void prep_kernel(const float* __restrict__ W_rec,
                            int* __restrict__ meta, char* __restrict__ wsB) {
    __shared__ int cnt[NN], sorted[NN], rowOff[NN];
    const int t = threadIdx.x;

    // zero stream region (pads + prefetch-overrun tail): 48KB
    for (int i = t; i < 49152 / 4; i += 256) ((int*)(wsB + STREAM_BASE))[i] = 0;

    if (t < NN) {
        int c = 0;
        for (int j = 0; j < NN; ++j) c += (W_rec[t * NN + j] != 0.0f);
        cnt[t] = c;
    }
    __syncthreads();
    if (t < NN) {   // deterministic descending rank (ties by index)
        int ct = cnt[t], r = 0;
        for (int j = 0; j < NN; ++j) {
            int cj = cnt[j];
            r += (cj > ct) || (cj == ct && j < t);
        }
        sorted[r] = t;
    }
    __syncthreads();
    if (t == 0) {
        int off = 0;
        for (int w = 0; w < 16; ++w) {
            int* m = meta + w * META_STRIDE;
            m[0] = off;                          // wave base entry index
            for (int r = 0; r < SLOTS; ++r) {
                int pos = (r & 1) ? (15 - w) : w;        // snake deal
                int row = sorted[r * 16 + pos];
                int c = cnt[row];
                int kp = ((c < 1 ? 1 : c) + 3) & ~3;     // pad to x4, min 4
                m[1 + r]  = row;
                m[10 + r] = kp;
                rowOff[row] = off;
                off += kp;
            }
        }
    }
    __syncthreads();
    if (t < NN) {            // fill each row's entries at its offset
        char* base = wsB + STREAM_BASE + (size_t)rowOff[t] * 8;
        int k = 0;
        for (int j = 0; j < NN; ++j) {
            float w = W_rec[t * NN + j];
            if (w != 0.0f) {
                *(unsigned*)(base + (size_t)k * 8)     = (unsigned)j * 256u;
                *(float*)(base + (size_t)k * 8 + 4)    = w;
                ++k;
            }
        }
        // (pads already zeroed; zero pads are exact +0.0*acc[0] no-ops)
    }
}

// 4 entries from two uint4 regs: {colByte,w}; DUAL alternating f64 accs.
#define GFMA4(S0, S1)                                                   \
    {                                                                   \
        float a0 = *(const float*)(ldsB + ((S0).x + lro));              \
        float a1 = *(const float*)(ldsB + ((S0).z + lro));              \
        float a2 = *(const float*)(ldsB + ((S1).x + lro));              \
        float a3 = *(const float*)(ldsB + ((S1).z + lro));              \
        rec0 += (double)u2f((S0).y) * (double)a0;                       \
        rec1 += (double)u2f((S0).w) * (double)a1;                       \
        rec0 += (double)u2f((S1).y) * (double)a2;                       \
        rec1 += (double)u2f((S1).w) * (double)a3;                       \
    }

__global__ __launch_bounds__(THREADS) void snn_kernel(
        const int*   __restrict__ actions,
        const float* __restrict__ spk,      // [B,8,115]
        const float* __restrict__ W_inh,    // [144,115]
        const int*   __restrict__ meta,
        const uint4* __restrict__ csrQ,     // stream: 2 entries per uint4
        const int*   __restrict__ nt_ptr,
        float*       __restrict__ out,      // [B,115]
        int B) {
    __shared__ float accF[2][NN * NB];      // 73728 B, double-buffered
    __shared__ int   metaL[16 * META_STRIDE];

    const char* ldsB = (const char*)&accF[0][0];
    float* nbF = &accF[1][0];               // [NE][65] alias, pre-loop only

    const int t    = threadIdx.x;
    const int lane = t & 63;
    const int wid  = t >> 6;
    const int b0   = blockIdx.x * NB;
    const int b    = b0 + lane;
    const int ticks = *nt_ptr;

    // opaque per-lane zero: keeps the CSR stream on the vector VMEM path
    int vz;
    asm volatile("v_mov_b32 %0, 0" : "=v"(vz));

    if (t < 16 * META_STRIDE) metaL[t] = meta[t];

    // stage neighbor sums into nbF[e][bb]
    for (int p = t; p < NB * NE; p += THREADS) {
        int bb = p / NE;
        int e  = p - bb * NE;
        float s = 0.0f;
        if (b0 + bb < B) {
            const float* sp = spk + ((size_t)(b0 + bb) * 8) * NE + e;
            #pragma unroll
            for (int n = 0; n < 8; ++n) s += sp[n * NE];
        }
        nbF[e * (NB + 1) + bb] = s;
    }
    for (int i = t; i < NN * NB; i += THREADS) accF[0][i] = 0.0f;
    __syncthreads();

    // wave-uniform metadata (SGPRs)
    const int mb = wid * META_STRIDE;
    const int sbase = __builtin_amdgcn_readfirstlane(metaL[mb]);
    int rows[SLOTS], skp[SLOTS];
    #pragma unroll
    for (int r = 0; r < SLOTS; ++r) {
        rows[r] = __builtin_amdgcn_readfirstlane(metaL[mb + 1 + r]);
        skp[r]  = __builtin_amdgcn_readfirstlane(metaL[mb + 10 + r]);
    }

    // per-row drives (fp64, e ascending — same association as R4-R15)
    double drv[SLOTS];
    {
        int a = (b < B) ? actions[b] : 4;
        int cs = ((a == 0) ? 5 : (a == 1) ? 1 : (a == 2) ? 3 : (a == 3) ? 7 : 4) * 16;
        #pragma unroll
        for (int r = 0; r < SLOTS; ++r) {
            double inh = 0.0;
            for (int e = 0; e < NE; ++e)
                inh += (double)nbF[e * (NB + 1) + lane]
                     * (double)W_inh[rows[r] * NE + e];
            double ic = (rows[r] >= cs && rows[r] < cs + 16) ? 5.0 : 0.0;
            drv[r] = 0.5 * ic - 0.5 * inh;
        }
    }

    const uint4* pBase = csrQ + (sbase >> 1) + vz;   // per-lane ptr (VMEM)

    double v[SLOTS];
    float  accv[SLOTS];
    #pragma unroll
    for (int r = 0; r < SLOTS; ++r) { v[r] = 0.0; accv[r] = 0.0f; }

    for (int tk = 0; tk < ticks; ++tk) {
        __syncthreads();   // prev tick's acc writes (or initial zeros) visible
        const unsigned rbOff = (tk & 1) ? 36864u : 0u;
        const unsigned lro   = (unsigned)(lane * 4) + rbOff;
        char* WbB = (char*)ldsB + ((tk & 1) ? 0u : 36864u);

        // prime: SA = entries 0..3, SB = 4..7 of this wave's flat stream
        const uint4* p = pBase;
        uint4 SA0 = p[0], SA1 = p[1];
        uint4 SB0 = p[2], SB1 = p[3];

        #pragma unroll
        for (int r = 0; r < SLOTS; ++r) {
            double rec0 = 0.0, rec1 = 0.0;
            int k = 0;
            const int kend = skp[r];
            // steady state: 2 chunks (8 entries)/iter, zero rotation movs
            while (k + 8 <= kend) {
                GFMA4(SA0, SA1);
                SA0 = p[4]; SA1 = p[5];
                GFMA4(SB0, SB1);
                SB0 = p[6]; SB1 = p[7];
                p += 4; k += 8;
            }
            if (k < kend) {                  // kend%8==4 leftover chunk
                GFMA4(SA0, SA1);
                SA0 = SB0; SA1 = SB1;
                SB0 = p[4]; SB1 = p[5];
                p += 2;
            }
            // invariant: SA = next slot's first chunk, SB = second
            const int o = rows[r];
            double rec = rec0 + rec1;        // exact-f64-class reassociation
            double x = drv[r] + 0.3 * ((o < NE) ? rec : -rec);
            double vv = v[r];
            vv += (x - vv) * 0.5;
            double sd = (vv >= 1.0) ? 1.0 : 0.0;
            vv *= (1.0 - sd);
            v[r] = vv;
            accv[r] += (float)sd;
            *(float*)(WbB + ((unsigned)o << 8) + lane * 4) = accv[r];
        }
    }

    if (b < B) {
        #pragma unroll
        for (int r = 0; r < SLOTS; ++r) {
            int o = rows[r];
            if (o < NE) out[(size_t)b * NE + o] = accv[r];
        }
    }
}

extern "C" void kernel_launch(void* const* d_in, const int* in_sizes, int n_in,
                              void* d_out, int out_size, void* d_ws, size_t ws_size,
                              hipStream_t stream) {
    const int*   actions = (const int*)  d_in[0];
    const float* spk     = (const float*)d_in[1];
    const float* W_rec   = (const float*)d_in[2];
    const float* W_inh   = (const float*)d_in[3];
    const int*   nt      = (const int*)  d_in[4];
    float* out = (float*)d_out;
    int B = in_sizes[0];

    int*  meta = (int*)d_ws;
    char* wsB  = (char*)d_ws;
    const uint4* csrQ = (const uint4*)(wsB + STREAM_BASE);

    prep_kernel<<<1, 256, 0, stream>>>(W_rec, meta, wsB);
    int nblocks = (B + NB - 1) / NB;
    snn_kernel<<<nblocks, THREADS, 0, stream>>>(actions, spk, W_inh, meta, csrQ,
                                                nt, out, B);
}